// Round 28
// baseline (110.922 us; speedup 1.0000x reference)
//
#include <hip/hip_runtime.h>
#include <hip/hip_bf16.h>
#include <cmath>

#define S_ 2048
#define D_ 1024
#define H_ 16
#define HD_ 64
#define GM 4096
#define GN 1024
#define GK 1024
#define QSCALE 0.1803368801111f   // 0.125 * log2(e)
#define THR2   11.5415603f        // 8 * log2(e)

typedef __attribute__((ext_vector_type(4))) float f32x4;
typedef __attribute__((ext_vector_type(8))) short bf16x8;
typedef __attribute__((ext_vector_type(4))) short bf16x4;

__device__ __forceinline__ short f2bf(float f) {
    union { float f; unsigned u; } x; x.f = f;
    unsigned r = x.u + 0x7fffu + ((x.u >> 16) & 1u);  // RNE
    return (short)(r >> 16);
}
__device__ __forceinline__ short bftrunc(float f) {   // P in [0, 2^11.6]: truncation ok
    union { float f; unsigned u; } x; x.f = f;
    return (short)(x.u >> 16);
}
__device__ __forceinline__ void gload16(const short* g, short* l) {
    __builtin_amdgcn_global_load_lds((const __attribute__((address_space(1))) void*)g,
                                     (__attribute__((address_space(3))) void*)l, 16, 0, 0);
}

// ---------------- one-shot fp32->bf16 convert (x + 4 W) ----------------
__global__ __launch_bounds__(256) void cvt_all(
    const float* __restrict__ x,
    const float* __restrict__ w0, const float* __restrict__ w1,
    const float* __restrict__ w2, const float* __restrict__ w3,
    short* __restrict__ xb, short* __restrict__ Wb)
{
    const int bid = blockIdx.x;        // 0..2047 x ; 2048..4095 W (512 each)
    const float* src; short* dst; int loc;
    if (bid < 2048) { src = x; dst = xb; loc = bid; }
    else {
        int wsel = (bid - 2048) >> 9, wb = (bid - 2048) & 511;
        src = wsel == 0 ? w0 : wsel == 1 ? w1 : wsel == 2 ? w2 : w3;
        dst = Wb + ((size_t)wsel << 20);
        loc = wb;
    }
    int id = loc * 256 + threadIdx.x;
    const float* s = src + (size_t)id * 8;
    f32x4 a = *(const f32x4*)s;
    f32x4 b = *(const f32x4*)(s + 4);
    bf16x8 h;
    h[0] = f2bf(a[0]); h[1] = f2bf(a[1]); h[2] = f2bf(a[2]); h[3] = f2bf(a[3]);
    h[4] = f2bf(b[0]); h[5] = f2bf(b[1]); h[6] = f2bf(b[2]); h[7] = f2bf(b[3]);
    *(bf16x8*)(dst + (size_t)id * 8) = h;
}

// ---------------- fused QKV GEMM: 128x128 tile, BK=64 double-buffer (1 barrier/step) ----------------
__global__ __launch_bounds__(256) void gemm_qkv(
    const short* __restrict__ A, const short* __restrict__ W3,
    const float* __restrict__ bq, const float* __restrict__ bk, const float* __restrict__ bv,
    short* __restrict__ Qb, short* __restrict__ Kb, short* __restrict__ Vt)
{
    __shared__ short SMEM[32768];
    const int t = threadIdx.x, lane = t & 63, w = t >> 6;
    const int bid = blockIdx.x;
    const int xcd = bid & 7, idx = bid >> 3;   // 96 per XCD
    const int ntile = idx % 24, mloc = idx / 24;
    const int m0 = (xcd * 4 + mloc) * 128;
    const int n0g = ntile * 128;               // 0..2944
    const int wr = (w >> 1) * 64, wc = (w & 1) * 64;
    const int fr = lane & 15, g = lane >> 4;
    const int srow = lane >> 3;
    const int gslot = (lane & 7) ^ srow;       // pre-swizzled source slot (rule 21)
    const int rbase = w * 32;

    f32x4 acc[4][4] = {};

    #pragma unroll
    for (int i = 0; i < 4; ++i) {
        int row = rbase + i * 8 + srow;
        gload16(A  + (size_t)(m0 + row) * GK + gslot * 8, &SMEM[(rbase + i * 8) * 64]);
        gload16(W3 + (size_t)(n0g + row) * GK + gslot * 8, &SMEM[8192 + (rbase + i * 8) * 64]);
    }
    __syncthreads();

    int cur = 0;
    for (int t16 = 0; t16 < 16; ++t16) {
        if (t16 < 15) {                        // prefetch next K-step into buf^1
            int kt = (t16 + 1) * 64;
            short* Ad = &SMEM[(cur ^ 1) * 16384];
            short* Bd = &SMEM[(cur ^ 1) * 16384 + 8192];
            #pragma unroll
            for (int i = 0; i < 4; ++i) {
                int row = rbase + i * 8 + srow;
                gload16(A  + (size_t)(m0 + row) * GK + kt + gslot * 8, &Ad[(rbase + i * 8) * 64]);
                gload16(W3 + (size_t)(n0g + row) * GK + kt + gslot * 8, &Bd[(rbase + i * 8) * 64]);
            }
        }
        const char* Asc = (const char*)&SMEM[cur * 16384];
        const char* Bsc = (const char*)&SMEM[cur * 16384 + 8192];
        #pragma unroll
        for (int ks = 0; ks < 2; ++ks) {
            bf16x8 af[4], bf_[4];
            #pragma unroll
            for (int mb = 0; mb < 4; ++mb) {
                int row = wr + mb * 16 + fr;
                af[mb] = *(const bf16x8*)(Asc + row * 128 + (((ks * 4 + g) ^ (row & 7)) << 4));
            }
            #pragma unroll
            for (int nb = 0; nb < 4; ++nb) {
                int row = wc + nb * 16 + fr;
                bf_[nb] = *(const bf16x8*)(Bsc + row * 128 + (((ks * 4 + g) ^ (row & 7)) << 4));
            }
            #pragma unroll
            for (int mb = 0; mb < 4; ++mb)
                #pragma unroll
                for (int nb = 0; nb < 4; ++nb)
                    acc[mb][nb] = __builtin_amdgcn_mfma_f32_16x16x32_bf16(
                        af[mb], bf_[nb], acc[mb][nb], 0, 0, 0);
        }
        __syncthreads();                       // drains prefetch vmcnt AFTER the MFMAs
        cur ^= 1;
    }

    const int seg = n0g >> 10, nn = n0g & 1023;
    if (seg == 2) {                            // V: transpose to Vt[(b*16+h)*64+d][S_]
        short* Cs = SMEM;                      // [128 col][136 pad]; final loop barrier protects
        #pragma unroll
        for (int mb = 0; mb < 4; ++mb)
            #pragma unroll
            for (int nb = 0; nb < 4; ++nb) {
                int cl = wc + nb * 16 + fr;
                int rl_ = wr + mb * 16 + g * 4;
                float bvv = bv[nn + cl];
                bf16x4 hv;
                #pragma unroll
                for (int r = 0; r < 4; ++r) hv[r] = f2bf(acc[mb][nb][r] + bvv);
                *(bf16x4*)(Cs + cl * 136 + rl_) = hv;
            }
        __syncthreads();
        const int b = m0 >> 11;
        const int s_base = m0 & 2047;
        #pragma unroll
        for (int p = 0; p < 8; ++p) {
            int id = t + p * 256;
            int cl = id >> 4, ch = id & 15;
            int n = nn + cl;
            int h = n >> 6, d = n & 63;
            bf16x8 v = *(const bf16x8*)(Cs + cl * 136 + ch * 8);
            *(bf16x8*)(Vt + ((size_t)((b * 16 + h) * 64 + d)) * S_ + s_base + ch * 8) = v;
        }
    } else {
        const float* bp = seg ? bk : bq;
        short* dst = seg ? Kb : Qb;
        const float sc = seg ? 1.0f : QSCALE;
        #pragma unroll
        for (int mb = 0; mb < 4; ++mb)
            #pragma unroll
            for (int nb = 0; nb < 4; ++nb) {
                int grow = m0 + wr + mb * 16 + g * 4;
                int gcol = nn + wc + nb * 16 + fr;
                float bvv = bp[gcol];
                #pragma unroll
                for (int r = 0; r < 4; ++r)
                    dst[(size_t)(grow + r) * GN + gcol] = f2bf((acc[mb][nb][r] + bvv) * sc);
            }
    }
}

// ---------------- O-proj GEMM: 128x128 tile, BK=64 dbuf (qkv structure), grid 256 ----------------
__global__ __launch_bounds__(256) void gemm_o(
    const short* __restrict__ A, const short* __restrict__ W,
    const float* __restrict__ bias, float* __restrict__ C)
{
    __shared__ short SMEM[32768];
    const int t = threadIdx.x, lane = t & 63, w = t >> 6;
    const int bid = blockIdx.x;
    const int xcd = bid & 7, wk = bid >> 3;        // 32 per XCD
    const int m0 = (xcd * 4 + (wk & 3)) * 128;
    const int n0 = (wk >> 2) * 128;                // 8 n-tiles
    const int wr = (w >> 1) * 64, wc = (w & 1) * 64;
    const int fr = lane & 15, g = lane >> 4;
    const int srow = lane >> 3;
    const int gslot = (lane & 7) ^ srow;
    const int rbase = w * 32;

    f32x4 acc[4][4] = {};

    #pragma unroll
    for (int i = 0; i < 4; ++i) {
        int row = rbase + i * 8 + srow;
        gload16(A + (size_t)(m0 + row) * GK + gslot * 8, &SMEM[(rbase + i * 8) * 64]);
        gload16(W + (size_t)(n0 + row) * GK + gslot * 8, &SMEM[8192 + (rbase + i * 8) * 64]);
    }
    __syncthreads();

    int cur = 0;
    for (int t16 = 0; t16 < 16; ++t16) {
        if (t16 < 15) {
            int kt = (t16 + 1) * 64;
            short* Ad = &SMEM[(cur ^ 1) * 16384];
            short* Bd = &SMEM[(cur ^ 1) * 16384 + 8192];
            #pragma unroll
            for (int i = 0; i < 4; ++i) {
                int row = rbase + i * 8 + srow;
                gload16(A + (size_t)(m0 + row) * GK + kt + gslot * 8, &Ad[(rbase + i * 8) * 64]);
                gload16(W + (size_t)(n0 + row) * GK + kt + gslot * 8, &Bd[(rbase + i * 8) * 64]);
            }
        }
        const char* Asc = (const char*)&SMEM[cur * 16384];
        const char* Bsc = (const char*)&SMEM[cur * 16384 + 8192];
        #pragma unroll
        for (int ks = 0; ks < 2; ++ks) {
            bf16x8 af[4], bf_[4];
            #pragma unroll
            for (int mb = 0; mb < 4; ++mb) {
                int row = wr + mb * 16 + fr;
                af[mb] = *(const bf16x8*)(Asc + row * 128 + (((ks * 4 + g) ^ (row & 7)) << 4));
            }
            #pragma unroll
            for (int nb = 0; nb < 4; ++nb) {
                int row = wc + nb * 16 + fr;
                bf_[nb] = *(const bf16x8*)(Bsc + row * 128 + (((ks * 4 + g) ^ (row & 7)) << 4));
            }
            #pragma unroll
            for (int mb = 0; mb < 4; ++mb)
                #pragma unroll
                for (int nb = 0; nb < 4; ++nb)
                    acc[mb][nb] = __builtin_amdgcn_mfma_f32_16x16x32_bf16(
                        af[mb], bf_[nb], acc[mb][nb], 0, 0, 0);
        }
        __syncthreads();
        cur ^= 1;
    }

    #pragma unroll
    for (int mb = 0; mb < 4; ++mb)
        #pragma unroll
        for (int nb = 0; nb < 4; ++nb) {
            int grow = m0 + wr + mb * 16 + g * 4;
            int gcol = n0 + wc + nb * 16 + fr;
            float bvv = bias[gcol];
            #pragma unroll
            for (int r = 0; r < 4; ++r)
                C[(size_t)(grow + r) * GN + gcol] = acc[mb][nb][r] + bvv;
        }
}

// ---------------- MFMA flash attention: QBLK=64 (4 waves, 4/CU = 16 waves/CU) ----------------
// Measured optimum (R22-R27). Falsified alternatives: 2-wave/32q (68us), QBLK=128 (68us),
// 8 waves/CU pairing (55us), global-direct frags (150us), setprio (+2.3us), remaps (+4-5us).
__global__ __launch_bounds__(256) void attn_fwd_bf16(
    const short* __restrict__ Qb, const short* __restrict__ Kb,
    const short* __restrict__ Vtb, short* __restrict__ Ob)
{
    __shared__ short SK[2][4096];    // [64 k][64 d]
    __shared__ short SVT[2][4096];   // [64 d][64 j]
    __shared__ short SP[4][1024];    // per wave: [16 q][64 k]

    const int t = threadIdx.x, lane = t & 63, w = t >> 6;
    const int g = lane >> 4, fr = lane & 15;
    const int bid = blockIdx.x;
    const int xcd = bid & 7, idx = bid >> 3;       // 128 per XCD
    const int bh = xcd * 4 + (idx & 3);            // 4 heads/XCD: K+Vt L2-resident
    const int qt = 31 - (idx >> 2);                // longest first
    const int b = bh >> 4, h = bh & 15;
    const int q0 = qt * 64;
    const int wq0 = w * 16;
    const int nt = qt + 1;

    // loop-invariant Q fragments (B-operand), straight from global
    bf16x8 qf[2];
    #pragma unroll
    for (int ks = 0; ks < 2; ++ks)
        qf[ks] = *(const bf16x8*)(Qb + (size_t)(b * S_ + q0 + wq0 + fr) * D_
                                  + h * 64 + ks * 32 + g * 8);

    // staging sources (pre-swizzled slot, rule 21); each instr covers 8 rows x 128B
    const int srow8 = lane >> 3;
    const short* kp[2];              // prefetch pointers, advanced incrementally
    const short* vp[2];
    short* kd0[2]; short* kd1[2]; short* vd0[2]; short* vd1[2];
    #pragma unroll
    for (int i = 0; i < 2; ++i) {
        int row = w * 16 + i * 8 + srow8;
        int gsl = (lane & 7) ^ (row & 7);
        kp[i] = Kb + (size_t)(b * S_ + row) * D_ + h * 64 + gsl * 8;
        vp[i] = Vtb + (size_t)(bh * 64 + row) * S_ + gsl * 8;
        kd0[i] = &SK[0][(w * 16 + i * 8) * 64];  kd1[i] = &SK[1][(w * 16 + i * 8) * 64];
        vd0[i] = &SVT[0][(w * 16 + i * 8) * 64]; vd1[i] = &SVT[1][(w * 16 + i * 8) * 64];
    }
    short* SPw = &SP[w][0];
    const int qsw = fr & 7;

    // prologue: stage kt=0 into buf 0
    #pragma unroll
    for (int i = 0; i < 2; ++i) {
        gload16(kp[i], kd0[i]);
        gload16(vp[i], vd0[i]);
    }
    __syncthreads();

    f32x4 Oacc[4] = {};
    float m2 = -1e30f, lsum = 0.f;
    int cur = 0;

    for (int kt = 0; kt < nt; ++kt) {
        if (kt + 1 < nt) {                          // prefetch next k-tile into buf^1
            kp[0] += 64 * D_; kp[1] += 64 * D_;     // incremental advance (no 64-bit mul)
            vp[0] += 64;      vp[1] += 64;
            if (cur) {
                #pragma unroll
                for (int i = 0; i < 2; ++i) { gload16(kp[i], kd0[i]); gload16(vp[i], vd0[i]); }
            } else {
                #pragma unroll
                for (int i = 0; i < 2; ++i) { gload16(kp[i], kd1[i]); gload16(vp[i], vd1[i]); }
            }
        }
        const char* SKc = (const char*)(cur ? &SK[1][0] : &SK[0][0]);
        const char* SVc = (const char*)(cur ? &SVT[1][0] : &SVT[0][0]);

        // ---- S^T = K * Q^T ----
        f32x4 sacc[4] = {};
        #pragma unroll
        for (int ks = 0; ks < 2; ++ks) {
            #pragma unroll
            for (int mk = 0; mk < 4; ++mk) {
                int row = mk * 16 + fr;
                bf16x8 kf = *(const bf16x8*)(SKc + row * 128 + (((ks * 4 + g) ^ (row & 7)) << 4));
                sacc[mk] = __builtin_amdgcn_mfma_f32_16x16x32_bf16(kf, qf[ks], sacc[mk], 0, 0, 0);
            }
        }
        if (kt == qt) {                             // diagonal tile: causal mask (local)
            #pragma unroll
            for (int mk = 0; mk < 4; ++mk)
                #pragma unroll
                for (int r = 0; r < 4; ++r)
                    if (mk * 16 + g * 4 + r > wq0 + fr) sacc[mk][r] = -1e30f;
        }

        // ---- per-lane scalar softmax (tree reductions) + P store ----
        float mx[4];
        #pragma unroll
        for (int mk = 0; mk < 4; ++mk)
            mx[mk] = fmaxf(fmaxf(sacc[mk][0], sacc[mk][1]), fmaxf(sacc[mk][2], sacc[mk][3]));
        float rm = fmaxf(fmaxf(mx[0], mx[1]), fmaxf(mx[2], mx[3]));
        rm = fmaxf(rm, __shfl_xor(rm, 16));
        rm = fmaxf(rm, __shfl_xor(rm, 32));
        if (rm > m2 + THR2) {                       // defer-max (T13)
            float resc = exp2f(m2 - rm);
            m2 = rm;
            lsum *= resc;
            #pragma unroll
            for (int md = 0; md < 4; ++md)
                #pragma unroll
                for (int r = 0; r < 4; ++r) Oacc[md][r] *= resc;
        }
        float psk[4];
        #pragma unroll
        for (int mk = 0; mk < 4; ++mk) {
            float p0 = exp2f(sacc[mk][0] - m2);
            float p1 = exp2f(sacc[mk][1] - m2);
            float p2 = exp2f(sacc[mk][2] - m2);
            float p3 = exp2f(sacc[mk][3] - m2);
            psk[mk] = (p0 + p1) + (p2 + p3);
            bf16x4 pk;
            pk[0] = bftrunc(p0); pk[1] = bftrunc(p1);
            pk[2] = bftrunc(p2); pk[3] = bftrunc(p3);
            int k = mk * 16 + g * 4;
            *(bf16x4*)((char*)SPw + fr * 128 + (((k >> 3) ^ qsw) << 4) + ((k & 7) << 1)) = pk;
        }
        float ps = (psk[0] + psk[1]) + (psk[2] + psk[3]);
        ps += __shfl_xor(ps, 16);
        ps += __shfl_xor(ps, 32);
        lsum += ps;

        // ---- PV: O^T += V^T * P^T (SP wave-private) ----
        #pragma unroll
        for (int ks = 0; ks < 2; ++ks) {
            bf16x8 pf = *(const bf16x8*)((const char*)SPw + fr * 128 + (((ks * 4 + g) ^ qsw) << 4));
            #pragma unroll
            for (int md = 0; md < 4; ++md) {
                int row = md * 16 + fr;
                bf16x8 vf = *(const bf16x8*)(SVc + row * 128 + (((ks * 4 + g) ^ (row & 7)) << 4));
                Oacc[md] = __builtin_amdgcn_mfma_f32_16x16x32_bf16(vf, pf, Oacc[md], 0, 0, 0);
            }
        }
        __syncthreads();                            // drains prefetch vmcnt, releases bufs
        cur ^= 1;
    }

    const float rl = 1.f / lsum;
    const size_t orow = (size_t)(b * S_ + q0 + wq0 + fr) * D_ + h * 64;
    #pragma unroll
    for (int md = 0; md < 4; ++md) {
        bf16x4 ov;
        #pragma unroll
        for (int r = 0; r < 4; ++r) ov[r] = f2bf(Oacc[md][r] * rl);
        *(bf16x4*)(Ob + orow + md * 16 + g * 4) = ov;
    }
}

extern "C" void kernel_launch(void* const* d_in, const int* in_sizes, int n_in,
                              void* d_out, int out_size, void* d_ws, size_t ws_size,
                              hipStream_t stream)
{
    const float* x  = (const float*)d_in[0];
    // d_in[1] = mask (causal, computed analytically)
    const float* Wq = (const float*)d_in[2];
    const float* bq = (const float*)d_in[3];
    const float* Wk = (const float*)d_in[4];
    const float* bk = (const float*)d_in[5];
    const float* Wv = (const float*)d_in[6];
    const float* bv = (const float*)d_in[7];
    const float* Wo = (const float*)d_in[8];
    const float* bo = (const float*)d_in[9];
    float* out = (float*)d_out;

    const size_t MD = (size_t)GM * D_;
    short* xb = (short*)d_ws;                  // 8 MB
    short* Wb = xb + MD;                       // 4 x 2 MB
    short* Qb = Wb + 4 * (size_t)D_ * D_;      // 8 MB
    short* Kb = Qb + MD;                       // 8 MB
    short* Vt = Kb + MD;                       // 8 MB
    short* Ob = Vt + MD;                       // 8 MB

    dim3 blk(256);
    cvt_all<<<dim3(4096), blk, 0, stream>>>(x, Wq, Wk, Wv, Wo, xb, Wb);
    gemm_qkv<<<dim3(768), blk, 0, stream>>>(xb, Wb, bq, bk, bv, Qb, Kb, Vt);
    attn_fwd_bf16<<<dim3(1024), blk, 0, stream>>>(Qb, Kb, Vt, Ob);
    gemm_o<<<dim3(256), blk, 0, stream>>>(Ob, Wb + 3 * (size_t)D_ * D_, bo, out);
}

// Round 29
// 110.576 us; speedup vs baseline: 1.0031x; 1.0031x over previous
//
#include <hip/hip_runtime.h>
#include <hip/hip_bf16.h>
#include <cmath>

#define S_ 2048
#define D_ 1024
#define H_ 16
#define HD_ 64
#define GM 4096
#define GN 1024
#define GK 1024
#define QSCALE 0.1803368801111f   // 0.125 * log2(e)
#define THR2   11.5415603f        // 8 * log2(e)

typedef __attribute__((ext_vector_type(4))) float f32x4;
typedef __attribute__((ext_vector_type(8))) short bf16x8;
typedef __attribute__((ext_vector_type(4))) short bf16x4;

__device__ __forceinline__ short f2bf(float f) {
    union { float f; unsigned u; } x; x.f = f;
    unsigned r = x.u + 0x7fffu + ((x.u >> 16) & 1u);  // RNE
    return (short)(r >> 16);
}
__device__ __forceinline__ short bftrunc(float f) {   // P in [0, 2^11.6]: truncation ok
    union { float f; unsigned u; } x; x.f = f;
    return (short)(x.u >> 16);
}
__device__ __forceinline__ void gload16(const short* g, short* l) {
    __builtin_amdgcn_global_load_lds((const __attribute__((address_space(1))) void*)g,
                                     (__attribute__((address_space(3))) void*)l, 16, 0, 0);
}

// ---------------- one-shot fp32->bf16 convert (x + 4 W) ----------------
__global__ __launch_bounds__(256) void cvt_all(
    const float* __restrict__ x,
    const float* __restrict__ w0, const float* __restrict__ w1,
    const float* __restrict__ w2, const float* __restrict__ w3,
    short* __restrict__ xb, short* __restrict__ Wb)
{
    const int bid = blockIdx.x;        // 0..2047 x ; 2048..4095 W (512 each)
    const float* src; short* dst; int loc;
    if (bid < 2048) { src = x; dst = xb; loc = bid; }
    else {
        int wsel = (bid - 2048) >> 9, wb = (bid - 2048) & 511;
        src = wsel == 0 ? w0 : wsel == 1 ? w1 : wsel == 2 ? w2 : w3;
        dst = Wb + ((size_t)wsel << 20);
        loc = wb;
    }
    int id = loc * 256 + threadIdx.x;
    const float* s = src + (size_t)id * 8;
    f32x4 a = *(const f32x4*)s;
    f32x4 b = *(const f32x4*)(s + 4);
    bf16x8 h;
    h[0] = f2bf(a[0]); h[1] = f2bf(a[1]); h[2] = f2bf(a[2]); h[3] = f2bf(a[3]);
    h[4] = f2bf(b[0]); h[5] = f2bf(b[1]); h[6] = f2bf(b[2]); h[7] = f2bf(b[3]);
    *(bf16x8*)(dst + (size_t)id * 8) = h;
}

// ---------------- fused QKV GEMM: 128x128 tile, BK=64 double-buffer (1 barrier/step) ----------------
__global__ __launch_bounds__(256) void gemm_qkv(
    const short* __restrict__ A, const short* __restrict__ W3,
    const float* __restrict__ bq, const float* __restrict__ bk, const float* __restrict__ bv,
    short* __restrict__ Qb, short* __restrict__ Kb, short* __restrict__ Vt)
{
    __shared__ short SMEM[32768];
    const int t = threadIdx.x, lane = t & 63, w = t >> 6;
    const int bid = blockIdx.x;
    const int xcd = bid & 7, idx = bid >> 3;   // 96 per XCD
    const int ntile = idx % 24, mloc = idx / 24;
    const int m0 = (xcd * 4 + mloc) * 128;
    const int n0g = ntile * 128;               // 0..2944
    const int wr = (w >> 1) * 64, wc = (w & 1) * 64;
    const int fr = lane & 15, g = lane >> 4;
    const int srow = lane >> 3;
    const int gslot = (lane & 7) ^ srow;       // pre-swizzled source slot (rule 21)
    const int rbase = w * 32;

    f32x4 acc[4][4] = {};

    #pragma unroll
    for (int i = 0; i < 4; ++i) {
        int row = rbase + i * 8 + srow;
        gload16(A  + (size_t)(m0 + row) * GK + gslot * 8, &SMEM[(rbase + i * 8) * 64]);
        gload16(W3 + (size_t)(n0g + row) * GK + gslot * 8, &SMEM[8192 + (rbase + i * 8) * 64]);
    }
    __syncthreads();

    int cur = 0;
    for (int t16 = 0; t16 < 16; ++t16) {
        if (t16 < 15) {                        // prefetch next K-step into buf^1
            int kt = (t16 + 1) * 64;
            short* Ad = &SMEM[(cur ^ 1) * 16384];
            short* Bd = &SMEM[(cur ^ 1) * 16384 + 8192];
            #pragma unroll
            for (int i = 0; i < 4; ++i) {
                int row = rbase + i * 8 + srow;
                gload16(A  + (size_t)(m0 + row) * GK + kt + gslot * 8, &Ad[(rbase + i * 8) * 64]);
                gload16(W3 + (size_t)(n0g + row) * GK + kt + gslot * 8, &Bd[(rbase + i * 8) * 64]);
            }
        }
        const char* Asc = (const char*)&SMEM[cur * 16384];
        const char* Bsc = (const char*)&SMEM[cur * 16384 + 8192];
        #pragma unroll
        for (int ks = 0; ks < 2; ++ks) {
            bf16x8 af[4], bf_[4];
            #pragma unroll
            for (int mb = 0; mb < 4; ++mb) {
                int row = wr + mb * 16 + fr;
                af[mb] = *(const bf16x8*)(Asc + row * 128 + (((ks * 4 + g) ^ (row & 7)) << 4));
            }
            #pragma unroll
            for (int nb = 0; nb < 4; ++nb) {
                int row = wc + nb * 16 + fr;
                bf_[nb] = *(const bf16x8*)(Bsc + row * 128 + (((ks * 4 + g) ^ (row & 7)) << 4));
            }
            #pragma unroll
            for (int mb = 0; mb < 4; ++mb)
                #pragma unroll
                for (int nb = 0; nb < 4; ++nb)
                    acc[mb][nb] = __builtin_amdgcn_mfma_f32_16x16x32_bf16(
                        af[mb], bf_[nb], acc[mb][nb], 0, 0, 0);
        }
        __syncthreads();                       // drains prefetch vmcnt AFTER the MFMAs
        cur ^= 1;
    }

    const int seg = n0g >> 10, nn = n0g & 1023;
    if (seg == 2) {                            // V: transpose to Vt[(b*16+h)*64+d][S_]
        short* Cs = SMEM;                      // [128 col][136 pad]; final loop barrier protects
        #pragma unroll
        for (int mb = 0; mb < 4; ++mb)
            #pragma unroll
            for (int nb = 0; nb < 4; ++nb) {
                int cl = wc + nb * 16 + fr;
                int rl_ = wr + mb * 16 + g * 4;
                float bvv = bv[nn + cl];
                bf16x4 hv;
                #pragma unroll
                for (int r = 0; r < 4; ++r) hv[r] = f2bf(acc[mb][nb][r] + bvv);
                *(bf16x4*)(Cs + cl * 136 + rl_) = hv;
            }
        __syncthreads();
        const int b = m0 >> 11;
        const int s_base = m0 & 2047;
        #pragma unroll
        for (int p = 0; p < 8; ++p) {
            int id = t + p * 256;
            int cl = id >> 4, ch = id & 15;
            int n = nn + cl;
            int h = n >> 6, d = n & 63;
            bf16x8 v = *(const bf16x8*)(Cs + cl * 136 + ch * 8);
            *(bf16x8*)(Vt + ((size_t)((b * 16 + h) * 64 + d)) * S_ + s_base + ch * 8) = v;
        }
    } else {
        const float* bp = seg ? bk : bq;
        short* dst = seg ? Kb : Qb;
        const float sc = seg ? 1.0f : QSCALE;
        #pragma unroll
        for (int mb = 0; mb < 4; ++mb)
            #pragma unroll
            for (int nb = 0; nb < 4; ++nb) {
                int grow = m0 + wr + mb * 16 + g * 4;
                int gcol = nn + wc + nb * 16 + fr;
                float bvv = bp[gcol];
                #pragma unroll
                for (int r = 0; r < 4; ++r)
                    dst[(size_t)(grow + r) * GN + gcol] = f2bf((acc[mb][nb][r] + bvv) * sc);
            }
    }
}

// ---------------- O-proj GEMM: 128x128 tile, BK=64 dbuf (qkv structure), grid 256 ----------------
__global__ __launch_bounds__(256) void gemm_o(
    const short* __restrict__ A, const short* __restrict__ W,
    const float* __restrict__ bias, float* __restrict__ C)
{
    __shared__ short SMEM[32768];
    const int t = threadIdx.x, lane = t & 63, w = t >> 6;
    const int bid = blockIdx.x;
    const int xcd = bid & 7, wk = bid >> 3;        // 32 per XCD
    const int m0 = (xcd * 4 + (wk & 3)) * 128;
    const int n0 = (wk >> 2) * 128;                // 8 n-tiles
    const int wr = (w >> 1) * 64, wc = (w & 1) * 64;
    const int fr = lane & 15, g = lane >> 4;
    const int srow = lane >> 3;
    const int gslot = (lane & 7) ^ srow;
    const int rbase = w * 32;

    f32x4 acc[4][4] = {};

    #pragma unroll
    for (int i = 0; i < 4; ++i) {
        int row = rbase + i * 8 + srow;
        gload16(A + (size_t)(m0 + row) * GK + gslot * 8, &SMEM[(rbase + i * 8) * 64]);
        gload16(W + (size_t)(n0 + row) * GK + gslot * 8, &SMEM[8192 + (rbase + i * 8) * 64]);
    }
    __syncthreads();

    int cur = 0;
    for (int t16 = 0; t16 < 16; ++t16) {
        if (t16 < 15) {
            int kt = (t16 + 1) * 64;
            short* Ad = &SMEM[(cur ^ 1) * 16384];
            short* Bd = &SMEM[(cur ^ 1) * 16384 + 8192];
            #pragma unroll
            for (int i = 0; i < 4; ++i) {
                int row = rbase + i * 8 + srow;
                gload16(A + (size_t)(m0 + row) * GK + kt + gslot * 8, &Ad[(rbase + i * 8) * 64]);
                gload16(W + (size_t)(n0 + row) * GK + kt + gslot * 8, &Bd[(rbase + i * 8) * 64]);
            }
        }
        const char* Asc = (const char*)&SMEM[cur * 16384];
        const char* Bsc = (const char*)&SMEM[cur * 16384 + 8192];
        #pragma unroll
        for (int ks = 0; ks < 2; ++ks) {
            bf16x8 af[4], bf_[4];
            #pragma unroll
            for (int mb = 0; mb < 4; ++mb) {
                int row = wr + mb * 16 + fr;
                af[mb] = *(const bf16x8*)(Asc + row * 128 + (((ks * 4 + g) ^ (row & 7)) << 4));
            }
            #pragma unroll
            for (int nb = 0; nb < 4; ++nb) {
                int row = wc + nb * 16 + fr;
                bf_[nb] = *(const bf16x8*)(Bsc + row * 128 + (((ks * 4 + g) ^ (row & 7)) << 4));
            }
            #pragma unroll
            for (int mb = 0; mb < 4; ++mb)
                #pragma unroll
                for (int nb = 0; nb < 4; ++nb)
                    acc[mb][nb] = __builtin_amdgcn_mfma_f32_16x16x32_bf16(
                        af[mb], bf_[nb], acc[mb][nb], 0, 0, 0);
        }
        __syncthreads();
        cur ^= 1;
    }

    #pragma unroll
    for (int mb = 0; mb < 4; ++mb)
        #pragma unroll
        for (int nb = 0; nb < 4; ++nb) {
            int grow = m0 + wr + mb * 16 + g * 4;
            int gcol = n0 + wc + nb * 16 + fr;
            float bvv = bias[gcol];
            #pragma unroll
            for (int r = 0; r < 4; ++r)
                C[(size_t)(grow + r) * GN + gcol] = acc[mb][nb][r] + bvv;
        }
}

// ---------------- MFMA flash attention: QBLK=64 (4 waves, 4/CU = 16 waves/CU) ----------------
// Measured optimum (R22-R28). Falsified alternatives: 2-wave/32q (68us), QBLK=128 (68us),
// 8 waves/CU pairing (55us), global-direct frags (150us), setprio (+2.3us), remaps (+4-5us).
__global__ __launch_bounds__(256) void attn_fwd_bf16(
    const short* __restrict__ Qb, const short* __restrict__ Kb,
    const short* __restrict__ Vtb, short* __restrict__ Ob)
{
    __shared__ short SK[2][4096];    // [64 k][64 d]
    __shared__ short SVT[2][4096];   // [64 d][64 j]
    __shared__ short SP[4][1024];    // per wave: [16 q][64 k]

    const int t = threadIdx.x, lane = t & 63, w = t >> 6;
    const int g = lane >> 4, fr = lane & 15;
    const int bid = blockIdx.x;
    const int xcd = bid & 7, idx = bid >> 3;       // 128 per XCD
    const int bh = xcd * 4 + (idx & 3);            // 4 heads/XCD: K+Vt L2-resident
    const int qt = 31 - (idx >> 2);                // longest first
    const int b = bh >> 4, h = bh & 15;
    const int q0 = qt * 64;
    const int wq0 = w * 16;
    const int nt = qt + 1;

    // loop-invariant Q fragments (B-operand), straight from global
    bf16x8 qf[2];
    #pragma unroll
    for (int ks = 0; ks < 2; ++ks)
        qf[ks] = *(const bf16x8*)(Qb + (size_t)(b * S_ + q0 + wq0 + fr) * D_
                                  + h * 64 + ks * 32 + g * 8);

    // staging sources (pre-swizzled slot, rule 21); each instr covers 8 rows x 128B
    const int srow8 = lane >> 3;
    const short* kp[2];              // prefetch pointers, advanced incrementally
    const short* vp[2];
    short* kd0[2]; short* kd1[2]; short* vd0[2]; short* vd1[2];
    #pragma unroll
    for (int i = 0; i < 2; ++i) {
        int row = w * 16 + i * 8 + srow8;
        int gsl = (lane & 7) ^ (row & 7);
        kp[i] = Kb + (size_t)(b * S_ + row) * D_ + h * 64 + gsl * 8;
        vp[i] = Vtb + (size_t)(bh * 64 + row) * S_ + gsl * 8;
        kd0[i] = &SK[0][(w * 16 + i * 8) * 64];  kd1[i] = &SK[1][(w * 16 + i * 8) * 64];
        vd0[i] = &SVT[0][(w * 16 + i * 8) * 64]; vd1[i] = &SVT[1][(w * 16 + i * 8) * 64];
    }
    short* SPw = &SP[w][0];
    const int qsw = fr & 7;

    // prologue: stage kt=0 into buf 0
    #pragma unroll
    for (int i = 0; i < 2; ++i) {
        gload16(kp[i], kd0[i]);
        gload16(vp[i], vd0[i]);
    }
    __syncthreads();

    f32x4 Oacc[4] = {};
    float m2 = -1e30f, lsum = 0.f;
    int cur = 0;

    for (int kt = 0; kt < nt; ++kt) {
        if (kt + 1 < nt) {                          // prefetch next k-tile into buf^1
            kp[0] += 64 * D_; kp[1] += 64 * D_;     // incremental advance (no 64-bit mul)
            vp[0] += 64;      vp[1] += 64;
            if (cur) {
                #pragma unroll
                for (int i = 0; i < 2; ++i) { gload16(kp[i], kd0[i]); gload16(vp[i], vd0[i]); }
            } else {
                #pragma unroll
                for (int i = 0; i < 2; ++i) { gload16(kp[i], kd1[i]); gload16(vp[i], vd1[i]); }
            }
        }
        const char* SKc = (const char*)(cur ? &SK[1][0] : &SK[0][0]);
        const char* SVc = (const char*)(cur ? &SVT[1][0] : &SVT[0][0]);

        // ---- S^T = K * Q^T ----
        f32x4 sacc[4] = {};
        #pragma unroll
        for (int ks = 0; ks < 2; ++ks) {
            #pragma unroll
            for (int mk = 0; mk < 4; ++mk) {
                int row = mk * 16 + fr;
                bf16x8 kf = *(const bf16x8*)(SKc + row * 128 + (((ks * 4 + g) ^ (row & 7)) << 4));
                sacc[mk] = __builtin_amdgcn_mfma_f32_16x16x32_bf16(kf, qf[ks], sacc[mk], 0, 0, 0);
            }
        }
        if (kt == qt) {                             // diagonal tile: causal mask (local)
            #pragma unroll
            for (int mk = 0; mk < 4; ++mk)
                #pragma unroll
                for (int r = 0; r < 4; ++r)
                    if (mk * 16 + g * 4 + r > wq0 + fr) sacc[mk][r] = -1e30f;
        }

        // ---- per-lane scalar softmax (tree reductions) + P store ----
        float mx[4];
        #pragma unroll
        for (int mk = 0; mk < 4; ++mk)
            mx[mk] = fmaxf(fmaxf(sacc[mk][0], sacc[mk][1]), fmaxf(sacc[mk][2], sacc[mk][3]));
        float rm = fmaxf(fmaxf(mx[0], mx[1]), fmaxf(mx[2], mx[3]));
        rm = fmaxf(rm, __shfl_xor(rm, 16));
        rm = fmaxf(rm, __shfl_xor(rm, 32));
        if (rm > m2 + THR2) {                       // defer-max (T13)
            float resc = exp2f(m2 - rm);
            m2 = rm;
            lsum *= resc;
            #pragma unroll
            for (int md = 0; md < 4; ++md)
                #pragma unroll
                for (int r = 0; r < 4; ++r) Oacc[md][r] *= resc;
        }
        float psk[4];
        #pragma unroll
        for (int mk = 0; mk < 4; ++mk) {
            float p0 = exp2f(sacc[mk][0] - m2);
            float p1 = exp2f(sacc[mk][1] - m2);
            float p2 = exp2f(sacc[mk][2] - m2);
            float p3 = exp2f(sacc[mk][3] - m2);
            psk[mk] = (p0 + p1) + (p2 + p3);
            bf16x4 pk;
            pk[0] = bftrunc(p0); pk[1] = bftrunc(p1);
            pk[2] = bftrunc(p2); pk[3] = bftrunc(p3);
            int k = mk * 16 + g * 4;
            *(bf16x4*)((char*)SPw + fr * 128 + (((k >> 3) ^ qsw) << 4) + ((k & 7) << 1)) = pk;
        }
        float ps = (psk[0] + psk[1]) + (psk[2] + psk[3]);
        ps += __shfl_xor(ps, 16);
        ps += __shfl_xor(ps, 32);
        lsum += ps;

        // ---- PV: O^T += V^T * P^T (SP wave-private) ----
        #pragma unroll
        for (int ks = 0; ks < 2; ++ks) {
            bf16x8 pf = *(const bf16x8*)((const char*)SPw + fr * 128 + (((ks * 4 + g) ^ qsw) << 4));
            #pragma unroll
            for (int md = 0; md < 4; ++md) {
                int row = md * 16 + fr;
                bf16x8 vf = *(const bf16x8*)(SVc + row * 128 + (((ks * 4 + g) ^ (row & 7)) << 4));
                Oacc[md] = __builtin_amdgcn_mfma_f32_16x16x32_bf16(vf, pf, Oacc[md], 0, 0, 0);
            }
        }
        __syncthreads();                            // drains prefetch vmcnt, releases bufs
        cur ^= 1;
    }

    const float rl = 1.f / lsum;
    const size_t orow = (size_t)(b * S_ + q0 + wq0 + fr) * D_ + h * 64;
    #pragma unroll
    for (int md = 0; md < 4; ++md) {
        bf16x4 ov;
        #pragma unroll
        for (int r = 0; r < 4; ++r) ov[r] = f2bf(Oacc[md][r] * rl);
        *(bf16x4*)(Ob + orow + md * 16 + g * 4) = ov;
    }
}

extern "C" void kernel_launch(void* const* d_in, const int* in_sizes, int n_in,
                              void* d_out, int out_size, void* d_ws, size_t ws_size,
                              hipStream_t stream)
{
    const float* x  = (const float*)d_in[0];
    // d_in[1] = mask (causal, computed analytically)
    const float* Wq = (const float*)d_in[2];
    const float* bq = (const float*)d_in[3];
    const float* Wk = (const float*)d_in[4];
    const float* bk = (const float*)d_in[5];
    const float* Wv = (const float*)d_in[6];
    const float* bv = (const float*)d_in[7];
    const float* Wo = (const float*)d_in[8];
    const float* bo = (const float*)d_in[9];
    float* out = (float*)d_out;

    const size_t MD = (size_t)GM * D_;
    short* xb = (short*)d_ws;                  // 8 MB
    short* Wb = xb + MD;                       // 4 x 2 MB
    short* Qb = Wb + 4 * (size_t)D_ * D_;      // 8 MB
    short* Kb = Qb + MD;                       // 8 MB
    short* Vt = Kb + MD;                       // 8 MB
    short* Ob = Vt + MD;                       // 8 MB

    dim3 blk(256);
    cvt_all<<<dim3(4096), blk, 0, stream>>>(x, Wq, Wk, Wv, Wo, xb, Wb);
    gemm_qkv<<<dim3(768), blk, 0, stream>>>(xb, Wb, bq, bk, bv, Qb, Kb, Vt);
    attn_fwd_bf16<<<dim3(1024), blk, 0, stream>>>(Qb, Kb, Vt, Ob);
    gemm_o<<<dim3(256), blk, 0, stream>>>(Ob, Wb + 3 * (size_t)D_ * D_, bo, out);
}